// Round 14
// baseline (416.992 us; speedup 1.0000x reference)
//
#include <hip/hip_runtime.h>
#include <hip/hip_bf16.h>
#include <math.h>

#define N_ATOMS 4096
#define N_EDGES 131072
#define PI6 0.52359877559829887308f

typedef __attribute__((ext_vector_type(4))) float f32x4;
typedef _Float16 h16;
typedef __attribute__((ext_vector_type(8))) _Float16 half8;

__device__ __forceinline__ float silu_f(float x) { return x / (1.0f + __expf(-x)); }

__device__ __forceinline__ unsigned pk2h(float lo, float hi) {
    h16 a = (h16)lo, b = (h16)hi;
    unsigned short ua, ub;
    __builtin_memcpy(&ua, &a, 2);
    __builtin_memcpy(&ub, &b, 2);
    return ((unsigned)ub << 16) | (unsigned)ua;
}

// ---------------------------------------------------------------------------
// Counting sort of edges by dst.
// ---------------------------------------------------------------------------
__global__ void count_kernel(const int* __restrict__ eidx, int* __restrict__ deg)
{
    int e = blockIdx.x * 256 + threadIdx.x;
    atomicAdd(&deg[eidx[N_EDGES + e]], 1);
}

__global__ void scan_kernel(const int* __restrict__ deg, int* __restrict__ base,
                            int* __restrict__ cur)
{
    __shared__ int sums[1024];
    const int t = threadIdx.x;
    int v0 = deg[4*t], v1 = deg[4*t+1], v2 = deg[4*t+2], v3 = deg[4*t+3];
    int s = v0 + v1 + v2 + v3;
    sums[t] = s;
    __syncthreads();
    for (int off = 1; off < 1024; off <<= 1) {
        int x = (t >= off) ? sums[t - off] : 0;
        __syncthreads();
        sums[t] += x;
        __syncthreads();
    }
    int excl = (t > 0) ? sums[t - 1] : 0;
    base[4*t]   = excl;             cur[4*t]   = excl;
    base[4*t+1] = excl + v0;        cur[4*t+1] = excl + v0;
    base[4*t+2] = excl + v0 + v1;   cur[4*t+2] = excl + v0 + v1;
    base[4*t+3] = excl + v0 + v1 + v2; cur[4*t+3] = excl + v0 + v1 + v2;
}

__global__ void scatter_kernel(const int* __restrict__ eidx, int* __restrict__ cur,
                               int* __restrict__ sortedE)
{
    int e = blockIdx.x * 256 + threadIdx.x;
    int dst = eidx[N_EDGES + e];
    int p = atomicAdd(&cur[dst], 1);
    sortedE[p] = e;
}

// ---------------------------------------------------------------------------
// Aggregation v4: WAVE-PER-ATOM, zero LDS, zero barriers. 4 waves/block,
// 512 blocks/pass, atoms [aoff + blk*4 + wave]. Per 2-edge chunk:
//   scalars (redundant on all lanes, broadcast loads) -> R1 in regs
//   (lane=ko, Wr1 column cached) -> R2 via __shfl(r1,j) + coalesced Wr2
//   float2 -> G[9][2] per-lane (channels 2*lane, 2*lane+1).
// Writes Gm[aloc][1152]. All f32, deterministic per sortedE order.
// ---------------------------------------------------------------------------
__global__ __launch_bounds__(256) void agg_kernel(
    const float* __restrict__ evec, const float* __restrict__ elen,
    const int* __restrict__ sortedE, const int* __restrict__ base,
    const int* __restrict__ deg, int aoff,
    const float* __restrict__ Wr1, const float* __restrict__ br1,
    const float* __restrict__ Wr2, const float* __restrict__ br2,
    float* __restrict__ Gm)
{
    const int t = threadIdx.x;
    const int lane = t & 63;
    const int wv = t >> 6;
    const int aloc = blockIdx.x * 4 + wv;
    const int dst = aoff + aloc;
    const int dg = deg[dst];
    const int bs = base[dst];
    const int c2 = lane * 2;

    float wr1[8];
    #pragma unroll
    for (int f = 0; f < 8; ++f) wr1[f] = Wr1[f * 64 + lane];
    const float br1v = br1[lane];
    const float2 b2v = *(const float2*)&br2[c2];

    float G[9][2] = {};

    for (int c0 = 0; c0 < dg; c0 += 2) {
        // ---- scalars for 2 edges, redundant on all lanes ----
        float rbf[2][8], sh[2][9];
        #pragma unroll
        for (int e = 0; e < 2; ++e) {
            int ce = c0 + e;
            if (ce < dg) {
                int eid = sortedE[bs + ce];
                float len = elen[eid];
                float th  = len * PI6;
                float snt = sinf(th), cst = cosf(th);
                float env = 0.5f * (cst + 1.0f) * (len < 6.0f ? 1.0f : 0.0f);
                float invl = env / len;
                float cc2 = 2.0f * cst;
                float skm = 0.f, sk = snt;
                #pragma unroll
                for (int f = 0; f < 8; ++f) {
                    rbf[e][f] = sk * invl;
                    float nx = fmaf(cc2, sk, -skm);
                    skm = sk; sk = nx;
                }
                float vx = evec[eid*3], vy = evec[eid*3+1], vz = evec[eid*3+2];
                float r = sqrtf(vx*vx + vy*vy + vz*vz) + 1e-8f;
                float inv = 1.0f / r;
                float x = vx*inv, y = vy*inv, z = vz*inv;
                sh[e][0] = 1.0f; sh[e][1] = y; sh[e][2] = z; sh[e][3] = x;
                sh[e][4] = 3.0f*z*z - 1.0f; sh[e][5] = x*z; sh[e][6] = y*z;
                sh[e][7] = x*y; sh[e][8] = x*x - y*y;
            } else {
                #pragma unroll
                for (int f = 0; f < 8; ++f) rbf[e][f] = 0.f;
                #pragma unroll
                for (int s = 0; s < 9; ++s) sh[e][s] = 0.f;
            }
        }
        // ---- R1 (lane = ko) ----
        float r1_0, r1_1;
        {
            float a0 = br1v, a1 = br1v;
            #pragma unroll
            for (int f = 0; f < 8; ++f) {
                a0 = fmaf(rbf[0][f], wr1[f], a0);
                a1 = fmaf(rbf[1][f], wr1[f], a1);
            }
            r1_0 = silu_f(a0);
            r1_1 = silu_f(a1);
        }
        // ---- R2 (channels c2, c2+1) via lane broadcast ----
        float a00 = 0.f, a01 = 0.f, a10 = 0.f, a11 = 0.f;
        #pragma unroll 8
        for (int j = 0; j < 64; ++j) {
            float2 w = *(const float2*)&Wr2[j * 128 + c2];
            float s0 = __shfl(r1_0, j);
            float s1 = __shfl(r1_1, j);
            a00 = fmaf(s0, w.x, a00);
            a01 = fmaf(s0, w.y, a01);
            a10 = fmaf(s1, w.x, a10);
            a11 = fmaf(s1, w.y, a11);
        }
        // ---- silu + G accumulate (sh is lane-local) ----
        {
            float ra = silu_f(a00 + b2v.x), rb = silu_f(a01 + b2v.y);
            #pragma unroll
            for (int s = 0; s < 9; ++s) {
                G[s][0] = fmaf(sh[0][s], ra, G[s][0]);
                G[s][1] = fmaf(sh[0][s], rb, G[s][1]);
            }
            float rc = silu_f(a10 + b2v.x), rd = silu_f(a11 + b2v.y);
            #pragma unroll
            for (int s = 0; s < 9; ++s) {
                G[s][0] = fmaf(sh[1][s], rc, G[s][0]);
                G[s][1] = fmaf(sh[1][s], rd, G[s][1]);
            }
        }
    }

    #pragma unroll
    for (int s = 0; s < 9; ++s) {
        float2 g2 = make_float2(G[s][0], G[s][1]);
        *(float2*)&Gm[(size_t)aloc * 1152 + s * 128 + c2] = g2;
    }
}

// ---------------------------------------------------------------------------
// gemm_gw_part (wprep fused): P[kk][m][o] = Gm[m][kk*128+k] @ Wtp[row(kk,k)][o]
// Grid (128 M-tiles of 16, 9 K-chunks). AT padded [128][17].
// ---------------------------------------------------------------------------
__global__ __launch_bounds__(256) void gemm_gw_part(
    const float* __restrict__ Gm, const float* __restrict__ Wtp,
    float* __restrict__ P)
{
    __shared__ __align__(16) float AT[128][17];
    __shared__ __align__(16) float Ws[128][64];
    const int t  = threadIdx.x;
    const int M0 = blockIdx.x * 16;
    const int kk = blockIdx.y;

    for (int idx = t; idx < 16 * 128; idx += 256) {
        int m = idx >> 7, k = idx & 127;
        AT[k][m] = Gm[(M0 + m) * 1152 + kk * 128 + k];
    }
    for (int idx = t; idx < 128 * 64; idx += 256) {
        int k = idx >> 6, o = idx & 63;
        int row = (kk == 0) ? k : (kk < 4 ? 128 + k * 3 + (kk - 1)
                                          : 512 + k * 5 + (kk - 4));
        Ws[k][o] = Wtp[row * 128 + o];
    }
    __syncthreads();

    const int m0 = t & 15;
    const int o0 = (t >> 4) * 4;
    f32x4 acc = {0.f, 0.f, 0.f, 0.f};
    #pragma unroll 4
    for (int k = 0; k < 128; ++k) {
        float a = AT[k][m0];
        f32x4 w = *(const f32x4*)&Ws[k][o0];
        acc += w * a;
    }
    *(f32x4*)&P[((size_t)kk * 2048 + M0 + m0) * 64 + o0] = acc;
}

// ---------------------------------------------------------------------------
// gw_reduce: agg[aoff+m][o] = sum_kk P[kk][m][o] + deg*btp. Fixed-order sum.
// ---------------------------------------------------------------------------
__global__ void gw_reduce(const float* __restrict__ P, const int* __restrict__ deg,
                          const float* __restrict__ btp, int aoff,
                          float* __restrict__ agg)
{
    int i = blockIdx.x * 256 + threadIdx.x;   // < 2048*64
    int m = i >> 6, o = i & 63;
    float s = 0.f;
    #pragma unroll
    for (int kk = 0; kk < 9; ++kk) s += P[(size_t)kk * 131072 + i];
    agg[(aoff + m) * 64 + o] = s + (float)deg[aoff + m] * btp[o];
}

// ---------------------------------------------------------------------------
// gemm_m1 (combined fused): A[m][k] = k<64 ? emb[an[m]][k] : agg[m][k-64];
// C = silu(A @ Wm1 + bm1), N=128.
// ---------------------------------------------------------------------------
__global__ __launch_bounds__(256, 2) void gemm_m1(
    const int* __restrict__ an, const float* __restrict__ emb,
    const float* __restrict__ agg, const float* __restrict__ W,
    const float* __restrict__ bias, float* __restrict__ C)
{
    __shared__ __align__(16) float AT[128][64];
    __shared__ __align__(16) float Ws[128][64];
    const int t  = threadIdx.x;
    const int M0 = blockIdx.x * 64;
    const int N0 = blockIdx.y * 64;

    for (int idx = t; idx < 64 * 128; idx += 256) {
        int m = idx >> 7, k = idx & 127;
        float v = (k < 64) ? emb[an[M0 + m] * 64 + k]
                           : agg[(M0 + m) * 64 + (k - 64)];
        AT[k][m ^ ((k & 15) << 2)] = v;
    }
    for (int idx = t; idx < 128 * 64; idx += 256) {
        int k = idx >> 6, o = idx & 63;
        Ws[k][o] = W[k * 128 + N0 + o];
    }
    __syncthreads();

    const int m0 = (t & 15) * 4;
    const int o0 = (t >> 4) * 4;
    float acc[4][4] = {};
    #pragma unroll 2
    for (int k = 0; k < 128; ++k) {
        int xs = (k & 15) << 2;
        float4 a4 = *(const float4*)&AT[k][m0 ^ xs];
        float4 w4 = *(const float4*)&Ws[k][o0];
        float av[4] = {a4.x, a4.y, a4.z, a4.w};
        float wv[4] = {w4.x, w4.y, w4.z, w4.w};
        #pragma unroll
        for (int i = 0; i < 4; ++i)
            #pragma unroll
            for (int j = 0; j < 4; ++j)
                acc[i][j] = fmaf(av[i], wv[j], acc[i][j]);
    }

    #pragma unroll
    for (int i = 0; i < 4; ++i) {
        int m = M0 + m0 + i;
        #pragma unroll
        for (int j = 0; j < 4; ++j) {
            int o = N0 + o0 + j;
            C[m * 128 + o] = silu_f(acc[i][j] + bias[o]);
        }
    }
}

// ---------------------------------------------------------------------------
// Generic node GEMM (f32): ACT 0 = none, 2 = gate epilogue.
// ---------------------------------------------------------------------------
template <int ACT>
__global__ __launch_bounds__(256, 2) void gemm128(
    const float* __restrict__ A, const float* __restrict__ W,
    const float* __restrict__ bias, float* __restrict__ C, int N,
    const float* __restrict__ aux1, const float* __restrict__ aux2)
{
    __shared__ __align__(16) float AT[128][64];
    __shared__ __align__(16) float Ws[128][64];
    const int t  = threadIdx.x;
    const int M0 = blockIdx.x * 64;
    const int N0 = blockIdx.y * 64;

    for (int idx = t; idx < 64 * 128; idx += 256) {
        int m = idx >> 7, k = idx & 127;
        AT[k][m ^ ((k & 15) << 2)] = A[(M0 + m) * 128 + k];
    }
    for (int idx = t; idx < 128 * 64; idx += 256) {
        int k = idx >> 6, o = idx & 63;
        Ws[k][o] = W[k * N + N0 + o];
    }
    __syncthreads();

    const int m0 = (t & 15) * 4;
    const int o0 = (t >> 4) * 4;
    float acc[4][4] = {};
    #pragma unroll 2
    for (int k = 0; k < 128; ++k) {
        int xs = (k & 15) << 2;
        float4 a4 = *(const float4*)&AT[k][m0 ^ xs];
        float4 w4 = *(const float4*)&Ws[k][o0];
        float av[4] = {a4.x, a4.y, a4.z, a4.w};
        float wv[4] = {w4.x, w4.y, w4.z, w4.w};
        #pragma unroll
        for (int i = 0; i < 4; ++i)
            #pragma unroll
            for (int j = 0; j < 4; ++j)
                acc[i][j] = fmaf(av[i], wv[j], acc[i][j]);
    }

    #pragma unroll
    for (int i = 0; i < 4; ++i) {
        int m = M0 + m0 + i;
        #pragma unroll
        for (int j = 0; j < 4; ++j) {
            int o = N0 + o0 + j;
            float v = acc[i][j] + bias[o];
            if (ACT == 2) {
                float sg = 1.0f / (1.0f + __expf(-v));
                v = sg * aux1[m * 128 + o] + (1.0f - sg) * aux2[m * 128 + o];
            }
            C[m * N + o] = v;
        }
    }
}

// ---------------------------------------------------------------------------
// gemm_qkv (qkvprep fused): C = upd @ Wqkv + bqkv, written DIRECTLY as fp16
// Qh/Kh [h][n][32] (Q pre-scaled) and VT [h*32+d][4096]. No f32 qkv buffer.
// ---------------------------------------------------------------------------
__global__ __launch_bounds__(256, 2) void gemm_qkv(
    const float* __restrict__ A, const float* __restrict__ W,
    const float* __restrict__ bias,
    h16* __restrict__ Qh, h16* __restrict__ Kh, h16* __restrict__ VT)
{
    __shared__ __align__(16) float AT[128][64];
    __shared__ __align__(16) float Ws[128][64];
    const int t  = threadIdx.x;
    const int M0 = blockIdx.x * 64;
    const int N0 = blockIdx.y * 64;

    for (int idx = t; idx < 64 * 128; idx += 256) {
        int m = idx >> 7, k = idx & 127;
        AT[k][m ^ ((k & 15) << 2)] = A[(M0 + m) * 128 + k];
    }
    for (int idx = t; idx < 128 * 64; idx += 256) {
        int k = idx >> 6, o = idx & 63;
        Ws[k][o] = W[k * 384 + N0 + o];
    }
    __syncthreads();

    const int m0 = (t & 15) * 4;
    const int o0 = (t >> 4) * 4;
    float acc[4][4] = {};
    #pragma unroll 2
    for (int k = 0; k < 128; ++k) {
        int xs = (k & 15) << 2;
        float4 a4 = *(const float4*)&AT[k][m0 ^ xs];
        float4 w4 = *(const float4*)&Ws[k][o0];
        float av[4] = {a4.x, a4.y, a4.z, a4.w};
        float wv[4] = {w4.x, w4.y, w4.z, w4.w};
        #pragma unroll
        for (int i = 0; i < 4; ++i)
            #pragma unroll
            for (int j = 0; j < 4; ++j)
                acc[i][j] = fmaf(av[i], wv[j], acc[i][j]);
    }

    const float scale = 0.17677669529663687f;
    #pragma unroll
    for (int i = 0; i < 4; ++i) {
        int m = M0 + m0 + i;
        #pragma unroll
        for (int j = 0; j < 4; ++j) {
            int o = N0 + o0 + j;
            float v = acc[i][j] + bias[o];
            if (o < 128) {
                Qh[((size_t)(o >> 5) * 4096 + m) * 32 + (o & 31)] = (h16)(v * scale);
            } else if (o < 256) {
                int oo = o - 128;
                Kh[((size_t)(oo >> 5) * 4096 + m) * 32 + (oo & 31)] = (h16)v;
            } else {
                VT[(size_t)(o - 256) * 4096 + m] = (h16)v;
            }
        }
    }
}

// ---------------------------------------------------------------------------
// Flash attention, fp16 MFMA, LDS-free main loop (validated R8).
// Block = (head, 16-row q-tile); 4 waves split KV 4-way; LDS merge at end.
// ---------------------------------------------------------------------------
__global__ __launch_bounds__(256, 4) void attn_kernel(
    const h16* __restrict__ Qh, const h16* __restrict__ Kh,
    const h16* __restrict__ VT, float* __restrict__ attd)
{
    __shared__ float st[4][64][10];
    const int t = threadIdx.x, w = t >> 6, lane = t & 63;
    const int h = blockIdx.x >> 8, qt = blockIdx.x & 255;
    const int l15 = lane & 15, g = lane >> 4;

    const h16* Kb = Kh + (size_t)h * 4096 * 32;
    const h16* Vb = VT + (size_t)h * 32 * 4096;
    half8 Qf = *(const half8*)(Qh + ((size_t)(h * 4096 + qt * 16 + l15) * 32 + g * 8));

    float m = -1e30f, l = 0.0f;
    f32x4 O0 = {0.f,0.f,0.f,0.f}, O1 = {0.f,0.f,0.f,0.f};
    const f32x4 zf = {0.f,0.f,0.f,0.f};
    const int sAlane = l15 + ((g & 1) << 5);
    const bool hi = g >= 2;

    const int kvbase = w * 1024;
    for (int kt = 0; kt < 32; ++kt) {
        int kv0 = kvbase + kt * 32;
        half8 K0 = *(const half8*)(Kb + ((size_t)(kv0 + l15) * 32 + g * 8));
        half8 K1 = *(const half8*)(Kb + ((size_t)(kv0 + 16 + l15) * 32 + g * 8));
        f32x4 S0 = __builtin_amdgcn_mfma_f32_16x16x32_f16(K0, Qf, zf, 0, 0, 0);
        f32x4 S1 = __builtin_amdgcn_mfma_f32_16x16x32_f16(K1, Qf, zf, 0, 0, 0);

        float tmax = fmaxf(fmaxf(fmaxf(S0.x, S0.y), fmaxf(S0.z, S0.w)),
                           fmaxf(fmaxf(S1.x, S1.y), fmaxf(S1.z, S1.w)));
        tmax = fmaxf(tmax, __shfl_xor(tmax, 16));
        tmax = fmaxf(tmax, __shfl_xor(tmax, 32));
        float mn = fmaxf(m, tmax);
        float c = __expf(m - mn);
        m = mn;
        float p0[4], p1[4];
        float ts = 0.f;
        #pragma unroll
        for (int i = 0; i < 4; ++i) { p0[i] = __expf(S0[i] - mn); ts += p0[i]; }
        #pragma unroll
        for (int i = 0; i < 4; ++i) { p1[i] = __expf(S1[i] - mn); ts += p1[i]; }
        ts += __shfl_xor(ts, 16);
        ts += __shfl_xor(ts, 32);
        l = l * c + ts;
        #pragma unroll
        for (int i = 0; i < 4; ++i) { O0[i] *= c; O1[i] *= c; }

        unsigned A0 = pk2h(p0[0], p0[1]), A1 = pk2h(p0[2], p0[3]);
        unsigned A2 = pk2h(p1[0], p1[1]), A3 = pk2h(p1[2], p1[3]);
        unsigned t0 = (unsigned)__shfl((int)A0, sAlane);
        unsigned t1 = (unsigned)__shfl((int)A1, sAlane);
        unsigned t2 = (unsigned)__shfl((int)A2, sAlane);
        unsigned t3 = (unsigned)__shfl((int)A3, sAlane);
        unsigned u0 = (unsigned)__shfl((int)A0, sAlane + 16);
        unsigned u1 = (unsigned)__shfl((int)A1, sAlane + 16);
        unsigned u2 = (unsigned)__shfl((int)A2, sAlane + 16);
        unsigned u3 = (unsigned)__shfl((int)A3, sAlane + 16);
        union { unsigned u[4]; half8 v; } P;
        P.u[0] = hi ? t2 : t0;
        P.u[1] = hi ? t3 : t1;
        P.u[2] = hi ? u2 : u0;
        P.u[3] = hi ? u3 : u1;

        half8 V0 = *(const half8*)(Vb + ((size_t)l15 * 4096 + kv0 + g * 8));
        half8 V1 = *(const half8*)(Vb + ((size_t)(16 + l15) * 4096 + kv0 + g * 8));
        O0 = __builtin_amdgcn_mfma_f32_16x16x32_f16(V0, P.v, O0, 0, 0, 0);
        O1 = __builtin_amdgcn_mfma_f32_16x16x32_f16(V1, P.v, O1, 0, 0, 0);
    }

    #pragma unroll
    for (int i = 0; i < 4; ++i) { st[w][lane][i] = O0[i]; st[w][lane][4 + i] = O1[i]; }
    st[w][lane][8] = m;
    st[w][lane][9] = l;
    __syncthreads();

    if (w == 0) {
        float M = -1e30f;
        #pragma unroll
        for (int j = 0; j < 4; ++j) M = fmaxf(M, st[j][lane][8]);
        float L = 0.f, o0[4] = {}, o1[4] = {};
        #pragma unroll
        for (int j = 0; j < 4; ++j) {
            float f = __expf(st[j][lane][8] - M);
            L += st[j][lane][9] * f;
            #pragma unroll
            for (int i = 0; i < 4; ++i) {
                o0[i] = fmaf(st[j][lane][i], f, o0[i]);
                o1[i] = fmaf(st[j][lane][4 + i], f, o1[i]);
            }
        }
        float invL = 1.0f / L;
        int nq = qt * 16 + l15;
        #pragma unroll
        for (int i = 0; i < 4; ++i) {
            attd[nq * 128 + h * 32 + g * 4 + i]      = o0[i] * invL;
            attd[nq * 128 + h * 32 + 16 + g * 4 + i] = o1[i] * invL;
        }
    }
}

// ---------------------------------------------------------------------------
extern "C" void kernel_launch(void* const* d_in, const int* in_sizes, int n_in,
                              void* d_out, int out_size, void* d_ws, size_t ws_size,
                              hipStream_t stream) {
    const int*   an    = (const int*)d_in[0];
    const int*   eidx  = (const int*)d_in[2];
    const float* evec  = (const float*)d_in[3];
    const float* elen  = (const float*)d_in[4];
    const float* emb   = (const float*)d_in[5];
    const float* Wr1   = (const float*)d_in[6];
    const float* br1   = (const float*)d_in[7];
    const float* Wr2   = (const float*)d_in[8];
    const float* br2   = (const float*)d_in[9];
    const float* Wtp   = (const float*)d_in[10];
    const float* btp   = (const float*)d_in[11];
    const float* Wm1   = (const float*)d_in[12];
    const float* bm1   = (const float*)d_in[13];
    const float* Wm2   = (const float*)d_in[14];
    const float* bm2   = (const float*)d_in[15];
    const float* Wqkv  = (const float*)d_in[16];
    const float* bqkv  = (const float*)d_in[17];
    const float* Wao   = (const float*)d_in[18];
    const float* bao   = (const float*)d_in[19];
    const float* Wg    = (const float*)d_in[20];
    const float* bg    = (const float*)d_in[21];
    const float* Wo    = (const float*)d_in[22];
    const float* bo    = (const float*)d_in[23];

    // workspace layout (floats), extent 4,456,448 f = 17.83 MB (R6-R13 proven):
    float* ws    = (float*)d_ws;
    float* agg   = ws;                       // [0, 262144)
    float* comb  = agg  + N_ATOMS * 64;      // [262144, 786432) region
    float* h1    = comb + N_ATOMS * 128;     // [786432, 1310720)
    float* upd   = h1   + N_ATOMS * 128;     // [1310720, 1835008)
    float* attd  = ws + 3407872;             // [3407872, 3932160)
    float* aob   = ws + 3932160;             // [3932160, 4456448)
    // time-disjoint aliases (liveness-audited):
    int*   deg     = (int*)aob;              // sort scratch in aob region;
    int*   base    = deg + 4096;             //  dead before aob written (t15)
    int*   cur     = base + 4096;
    int*   sortedE = cur + 4096;             // ends 4079616 < 4456448
    float* Gm    = comb;                     // per-half 2048*1152 f = [262144, 2621440)
    float* Pp    = ws + 2621440;             // 9*2048*64 f = [2621440, 3801088)
    float* outp  = comb;                     // comb region free after attn
    h16* Qhb = (h16*)comb;                   // [262144, 524288) f32-equiv
    h16* Khb = Qhb + 4 * 4096 * 32;          // [524288, 786432)
    h16* VTb = (h16*)h1;                     // h1 dead after gemm m2

    hipMemsetAsync(deg, 0, 4096 * sizeof(int), stream);

    count_kernel<<<512, 256, 0, stream>>>(eidx, deg);
    scan_kernel<<<1, 1024, 0, stream>>>(deg, base, cur);
    scatter_kernel<<<512, 256, 0, stream>>>(eidx, cur, sortedE);

    // agg in two half-passes (Gm 9.44 MB/half fits proven extent)
    agg_kernel<<<512, 256, 0, stream>>>(
        evec, elen, sortedE, base, deg, 0, Wr1, br1, Wr2, br2, Gm);
    gemm_gw_part<<<dim3(128, 9), 256, 0, stream>>>(Gm, Wtp, Pp);
    gw_reduce<<<512, 256, 0, stream>>>(Pp, deg, btp, 0, agg);
    agg_kernel<<<512, 256, 0, stream>>>(
        evec, elen, sortedE, base, deg, 2048, Wr1, br1, Wr2, br2, Gm);
    gemm_gw_part<<<dim3(128, 9), 256, 0, stream>>>(Gm, Wtp, Pp);
    gw_reduce<<<512, 256, 0, stream>>>(Pp, deg, btp, 2048, agg);

    gemm_m1<<<dim3(64, 2), 256, 0, stream>>>(an, emb, agg, Wm1, bm1, h1);
    gemm128<0><<<dim3(64, 2), 256, 0, stream>>>(h1, Wm2, bm2, upd, 128, nullptr, nullptr);
    gemm_qkv<<<dim3(64, 6), 256, 0, stream>>>(upd, Wqkv, bqkv, Qhb, Khb, VTb);

    attn_kernel<<<1024, 256, 0, stream>>>(Qhb, Khb, VTb, attd);

    gemm128<0><<<dim3(64, 2), 256, 0, stream>>>(attd, Wao, bao, aob, 128, nullptr, nullptr);
    gemm128<2><<<dim3(64, 2), 256, 0, stream>>>(upd, Wg, bg, outp, 128, aob, upd);
    gemm128<0><<<dim3(64, 2), 256, 0, stream>>>(outp, Wo, bo, (float*)d_out, 128, nullptr, nullptr);
}

// Round 15
// 352.450 us; speedup vs baseline: 1.1831x; 1.1831x over previous
//
#include <hip/hip_runtime.h>
#include <hip/hip_bf16.h>
#include <math.h>

#define N_ATOMS 4096
#define N_EDGES 131072
#define PI6 0.52359877559829887308f

typedef __attribute__((ext_vector_type(4))) float f32x4;
typedef _Float16 h16;
typedef __attribute__((ext_vector_type(8))) _Float16 half8;

__device__ __forceinline__ float silu_f(float x) { return x / (1.0f + __expf(-x)); }

__device__ __forceinline__ unsigned pk2h(float lo, float hi) {
    h16 a = (h16)lo, b = (h16)hi;
    unsigned short ua, ub;
    __builtin_memcpy(&ua, &a, 2);
    __builtin_memcpy(&ub, &b, 2);
    return ((unsigned)ub << 16) | (unsigned)ua;
}

// ---------------------------------------------------------------------------
// W-prep (f32): gather W_tp (only first 64 out-cols used downstream) into
// Wsl[f][o], f = s*128+c in [0,1152), o in [0,64). row(s,c) per reference.
// ---------------------------------------------------------------------------
__global__ void wprep_kernel(const float* __restrict__ Wtp, float* __restrict__ Wsl)
{
    int idx = blockIdx.x * 256 + threadIdx.x;     // < 9*128*64 = 73728
    int o = idx & 63;
    int c = (idx >> 6) & 127;
    int s = idx >> 13;
    int row = (s == 0) ? c : (s < 4 ? 128 + c * 3 + (s - 1) : 512 + c * 5 + (s - 4));
    Wsl[idx] = Wtp[row * 128 + o];
}

// ---------------------------------------------------------------------------
// Counting sort of edges by dst.
// ---------------------------------------------------------------------------
__global__ void count_kernel(const int* __restrict__ eidx, int* __restrict__ deg)
{
    int e = blockIdx.x * 256 + threadIdx.x;
    atomicAdd(&deg[eidx[N_EDGES + e]], 1);
}

__global__ void scan_kernel(const int* __restrict__ deg, int* __restrict__ base,
                            int* __restrict__ cur)
{
    __shared__ int sums[1024];
    const int t = threadIdx.x;
    int v0 = deg[4*t], v1 = deg[4*t+1], v2 = deg[4*t+2], v3 = deg[4*t+3];
    int s = v0 + v1 + v2 + v3;
    sums[t] = s;
    __syncthreads();
    for (int off = 1; off < 1024; off <<= 1) {
        int x = (t >= off) ? sums[t - off] : 0;
        __syncthreads();
        sums[t] += x;
        __syncthreads();
    }
    int excl = (t > 0) ? sums[t - 1] : 0;
    base[4*t]   = excl;             cur[4*t]   = excl;
    base[4*t+1] = excl + v0;        cur[4*t+1] = excl + v0;
    base[4*t+2] = excl + v0 + v1;   cur[4*t+2] = excl + v0 + v1;
    base[4*t+3] = excl + v0 + v1 + v2; cur[4*t+3] = excl + v0 + v1 + v2;
}

__global__ void scatter_kernel(const int* __restrict__ eidx, int* __restrict__ cur,
                               int* __restrict__ sortedE)
{
    int e = blockIdx.x * 256 + threadIdx.x;
    int dst = eidx[N_EDGES + e];
    int p = atomicAdd(&cur[dst], 1);
    sortedE[p] = e;
}

// ---------------------------------------------------------------------------
// Aggregation v5: SINGLE PASS, wave-per-atom edge phase (zero barriers) +
// fused 4-atom batched Wsl matvec. 1024 blocks x 256 thr (4 waves); wave w
// owns atom blk*4+w. Edge phase (R14-validated): per 2-edge chunk, scalars
// redundant on all lanes -> R1 (lane=ko, regs) -> R2 via __shfl broadcast +
// coalesced Wr2 float2 -> G[9][2] per lane. Then GL4[w] in LDS, one barrier,
// R13-validated batched matvec (one Wsl sweep/block) -> agg (+deg*btp).
// All f32, no atomics, deterministic.
// ---------------------------------------------------------------------------
__global__ __launch_bounds__(256) void agg_kernel(
    const float* __restrict__ evec, const float* __restrict__ elen,
    const int* __restrict__ sortedE, const int* __restrict__ base,
    const int* __restrict__ deg,
    const float* __restrict__ Wr1, const float* __restrict__ br1,
    const float* __restrict__ Wr2, const float* __restrict__ br2,
    const float* __restrict__ Wsl, const float* __restrict__ btp,
    float* __restrict__ agg)
{
    __shared__ __align__(16) float GL4[4][1152];
    __shared__ __align__(16) float redL2[4][64][4];   // [qq][o][a]

    const int t = threadIdx.x;
    const int lane = t & 63;
    const int wv = t >> 6;
    const int dst = blockIdx.x * 4 + wv;
    const int dg = deg[dst];
    const int bs = base[dst];
    const int c2 = lane * 2;

    float wr1[8];
    #pragma unroll
    for (int f = 0; f < 8; ++f) wr1[f] = Wr1[f * 64 + lane];
    const float br1v = br1[lane];
    const float2 b2v = *(const float2*)&br2[c2];

    float G[9][2] = {};

    for (int c0 = 0; c0 < dg; c0 += 2) {
        // ---- scalars for 2 edges, redundant on all lanes ----
        float rbf[2][8], sh[2][9];
        #pragma unroll
        for (int e = 0; e < 2; ++e) {
            int ce = c0 + e;
            if (ce < dg) {
                int eid = sortedE[bs + ce];
                float len = elen[eid];
                float th  = len * PI6;
                float snt = sinf(th), cst = cosf(th);
                float env = 0.5f * (cst + 1.0f) * (len < 6.0f ? 1.0f : 0.0f);
                float invl = env / len;
                float cc2 = 2.0f * cst;
                float skm = 0.f, sk = snt;
                #pragma unroll
                for (int f = 0; f < 8; ++f) {
                    rbf[e][f] = sk * invl;
                    float nx = fmaf(cc2, sk, -skm);
                    skm = sk; sk = nx;
                }
                float vx = evec[eid*3], vy = evec[eid*3+1], vz = evec[eid*3+2];
                float r = sqrtf(vx*vx + vy*vy + vz*vz) + 1e-8f;
                float inv = 1.0f / r;
                float x = vx*inv, y = vy*inv, z = vz*inv;
                sh[e][0] = 1.0f; sh[e][1] = y; sh[e][2] = z; sh[e][3] = x;
                sh[e][4] = 3.0f*z*z - 1.0f; sh[e][5] = x*z; sh[e][6] = y*z;
                sh[e][7] = x*y; sh[e][8] = x*x - y*y;
            } else {
                #pragma unroll
                for (int f = 0; f < 8; ++f) rbf[e][f] = 0.f;
                #pragma unroll
                for (int s = 0; s < 9; ++s) sh[e][s] = 0.f;
            }
        }
        // ---- R1 (lane = ko) ----
        float r1_0, r1_1;
        {
            float a0 = br1v, a1 = br1v;
            #pragma unroll
            for (int f = 0; f < 8; ++f) {
                a0 = fmaf(rbf[0][f], wr1[f], a0);
                a1 = fmaf(rbf[1][f], wr1[f], a1);
            }
            r1_0 = silu_f(a0);
            r1_1 = silu_f(a1);
        }
        // ---- R2 (channels c2, c2+1) via lane broadcast ----
        float a00 = 0.f, a01 = 0.f, a10 = 0.f, a11 = 0.f;
        #pragma unroll 8
        for (int j = 0; j < 64; ++j) {
            float2 w = *(const float2*)&Wr2[j * 128 + c2];
            float s0 = __shfl(r1_0, j);
            float s1 = __shfl(r1_1, j);
            a00 = fmaf(s0, w.x, a00);
            a01 = fmaf(s0, w.y, a01);
            a10 = fmaf(s1, w.x, a10);
            a11 = fmaf(s1, w.y, a11);
        }
        // ---- silu + G accumulate (sh is lane-local) ----
        {
            float ra = silu_f(a00 + b2v.x), rb = silu_f(a01 + b2v.y);
            #pragma unroll
            for (int s = 0; s < 9; ++s) {
                G[s][0] = fmaf(sh[0][s], ra, G[s][0]);
                G[s][1] = fmaf(sh[0][s], rb, G[s][1]);
            }
            float rc = silu_f(a10 + b2v.x), rd = silu_f(a11 + b2v.y);
            #pragma unroll
            for (int s = 0; s < 9; ++s) {
                G[s][0] = fmaf(sh[1][s], rc, G[s][0]);
                G[s][1] = fmaf(sh[1][s], rd, G[s][1]);
            }
        }
    }

    // ---- G -> LDS (per-wave slice, no races), one barrier ----
    #pragma unroll
    for (int s = 0; s < 9; ++s) {
        GL4[wv][s * 128 + c2]     = G[s][0];
        GL4[wv][s * 128 + c2 + 1] = G[s][1];
    }
    __syncthreads();

    // ---- batched matvec: one Wsl sweep for all 4 atoms (R13-validated) ----
    {
        const int o = t & 63, qq = t >> 6;
        f32x4 acc = {0.f, 0.f, 0.f, 0.f};
        for (int i = 0; i < 288; ++i) {
            int f = qq * 288 + i;
            float w = Wsl[f * 64 + o];
            acc[0] = fmaf(GL4[0][f], w, acc[0]);
            acc[1] = fmaf(GL4[1][f], w, acc[1]);
            acc[2] = fmaf(GL4[2][f], w, acc[2]);
            acc[3] = fmaf(GL4[3][f], w, acc[3]);
        }
        *(f32x4*)&redL2[qq][o][0] = acc;
    }
    __syncthreads();
    {
        int a2 = t >> 6, o2 = t & 63;
        float s = redL2[0][o2][a2] + redL2[1][o2][a2]
                + redL2[2][o2][a2] + redL2[3][o2][a2];
        int dsta = blockIdx.x * 4 + a2;
        agg[dsta * 64 + o2] = s + (float)deg[dsta] * btp[o2];
    }
}

// ---------------------------------------------------------------------------
// gemm_m1 (combined fused): A[m][k] = k<64 ? emb[an[m]][k] : agg[m][k-64];
// C = silu(A @ Wm1 + bm1), N=128.
// ---------------------------------------------------------------------------
__global__ __launch_bounds__(256, 2) void gemm_m1(
    const int* __restrict__ an, const float* __restrict__ emb,
    const float* __restrict__ agg, const float* __restrict__ W,
    const float* __restrict__ bias, float* __restrict__ C)
{
    __shared__ __align__(16) float AT[128][64];
    __shared__ __align__(16) float Ws[128][64];
    const int t  = threadIdx.x;
    const int M0 = blockIdx.x * 64;
    const int N0 = blockIdx.y * 64;

    for (int idx = t; idx < 64 * 128; idx += 256) {
        int m = idx >> 7, k = idx & 127;
        float v = (k < 64) ? emb[an[M0 + m] * 64 + k]
                           : agg[(M0 + m) * 64 + (k - 64)];
        AT[k][m ^ ((k & 15) << 2)] = v;
    }
    for (int idx = t; idx < 128 * 64; idx += 256) {
        int k = idx >> 6, o = idx & 63;
        Ws[k][o] = W[k * 128 + N0 + o];
    }
    __syncthreads();

    const int m0 = (t & 15) * 4;
    const int o0 = (t >> 4) * 4;
    float acc[4][4] = {};
    #pragma unroll 2
    for (int k = 0; k < 128; ++k) {
        int xs = (k & 15) << 2;
        float4 a4 = *(const float4*)&AT[k][m0 ^ xs];
        float4 w4 = *(const float4*)&Ws[k][o0];
        float av[4] = {a4.x, a4.y, a4.z, a4.w};
        float wv[4] = {w4.x, w4.y, w4.z, w4.w};
        #pragma unroll
        for (int i = 0; i < 4; ++i)
            #pragma unroll
            for (int j = 0; j < 4; ++j)
                acc[i][j] = fmaf(av[i], wv[j], acc[i][j]);
    }

    #pragma unroll
    for (int i = 0; i < 4; ++i) {
        int m = M0 + m0 + i;
        #pragma unroll
        for (int j = 0; j < 4; ++j) {
            int o = N0 + o0 + j;
            C[m * 128 + o] = silu_f(acc[i][j] + bias[o]);
        }
    }
}

// ---------------------------------------------------------------------------
// Generic node GEMM (f32): ACT 0 = none, 2 = gate epilogue.
// ---------------------------------------------------------------------------
template <int ACT>
__global__ __launch_bounds__(256, 2) void gemm128(
    const float* __restrict__ A, const float* __restrict__ W,
    const float* __restrict__ bias, float* __restrict__ C, int N,
    const float* __restrict__ aux1, const float* __restrict__ aux2)
{
    __shared__ __align__(16) float AT[128][64];
    __shared__ __align__(16) float Ws[128][64];
    const int t  = threadIdx.x;
    const int M0 = blockIdx.x * 64;
    const int N0 = blockIdx.y * 64;

    for (int idx = t; idx < 64 * 128; idx += 256) {
        int m = idx >> 7, k = idx & 127;
        AT[k][m ^ ((k & 15) << 2)] = A[(M0 + m) * 128 + k];
    }
    for (int idx = t; idx < 128 * 64; idx += 256) {
        int k = idx >> 6, o = idx & 63;
        Ws[k][o] = W[k * N + N0 + o];
    }
    __syncthreads();

    const int m0 = (t & 15) * 4;
    const int o0 = (t >> 4) * 4;
    float acc[4][4] = {};
    #pragma unroll 2
    for (int k = 0; k < 128; ++k) {
        int xs = (k & 15) << 2;
        float4 a4 = *(const float4*)&AT[k][m0 ^ xs];
        float4 w4 = *(const float4*)&Ws[k][o0];
        float av[4] = {a4.x, a4.y, a4.z, a4.w};
        float wv[4] = {w4.x, w4.y, w4.z, w4.w};
        #pragma unroll
        for (int i = 0; i < 4; ++i)
            #pragma unroll
            for (int j = 0; j < 4; ++j)
                acc[i][j] = fmaf(av[i], wv[j], acc[i][j]);
    }

    #pragma unroll
    for (int i = 0; i < 4; ++i) {
        int m = M0 + m0 + i;
        #pragma unroll
        for (int j = 0; j < 4; ++j) {
            int o = N0 + o0 + j;
            float v = acc[i][j] + bias[o];
            if (ACT == 2) {
                float sg = 1.0f / (1.0f + __expf(-v));
                v = sg * aux1[m * 128 + o] + (1.0f - sg) * aux2[m * 128 + o];
            }
            C[m * N + o] = v;
        }
    }
}

// ---------------------------------------------------------------------------
// gemm_qkv (qkvprep fused): C = upd @ Wqkv + bqkv, written DIRECTLY as fp16
// Qh/Kh [h][n][32] (Q pre-scaled) and VT [h*32+d][4096]. No f32 qkv buffer.
// ---------------------------------------------------------------------------
__global__ __launch_bounds__(256, 2) void gemm_qkv(
    const float* __restrict__ A, const float* __restrict__ W,
    const float* __restrict__ bias,
    h16* __restrict__ Qh, h16* __restrict__ Kh, h16* __restrict__ VT)
{
    __shared__ __align__(16) float AT[128][64];
    __shared__ __align__(16) float Ws[128][64];
    const int t  = threadIdx.x;
    const int M0 = blockIdx.x * 64;
    const int N0 = blockIdx.y * 64;

    for (int idx = t; idx < 64 * 128; idx += 256) {
        int m = idx >> 7, k = idx & 127;
        AT[k][m ^ ((k & 15) << 2)] = A[(M0 + m) * 128 + k];
    }
    for (int idx = t; idx < 128 * 64; idx += 256) {
        int k = idx >> 6, o = idx & 63;
        Ws[k][o] = W[k * 384 + N0 + o];
    }
    __syncthreads();

    const int m0 = (t & 15) * 4;
    const int o0 = (t >> 4) * 4;
    float acc[4][4] = {};
    #pragma unroll 2
    for (int k = 0; k < 128; ++k) {
        int xs = (k & 15) << 2;
        float4 a4 = *(const float4*)&AT[k][m0 ^ xs];
        float4 w4 = *(const float4*)&Ws[k][o0];
        float av[4] = {a4.x, a4.y, a4.z, a4.w};
        float wv[4] = {w4.x, w4.y, w4.z, w4.w};
        #pragma unroll
        for (int i = 0; i < 4; ++i)
            #pragma unroll
            for (int j = 0; j < 4; ++j)
                acc[i][j] = fmaf(av[i], wv[j], acc[i][j]);
    }

    const float scale = 0.17677669529663687f;
    #pragma unroll
    for (int i = 0; i < 4; ++i) {
        int m = M0 + m0 + i;
        #pragma unroll
        for (int j = 0; j < 4; ++j) {
            int o = N0 + o0 + j;
            float v = acc[i][j] + bias[o];
            if (o < 128) {
                Qh[((size_t)(o >> 5) * 4096 + m) * 32 + (o & 31)] = (h16)(v * scale);
            } else if (o < 256) {
                int oo = o - 128;
                Kh[((size_t)(oo >> 5) * 4096 + m) * 32 + (oo & 31)] = (h16)v;
            } else {
                VT[(size_t)(o - 256) * 4096 + m] = (h16)v;
            }
        }
    }
}

// ---------------------------------------------------------------------------
// Flash attention, fp16 MFMA, LDS-free main loop (validated R8).
// Block = (head, 16-row q-tile); 4 waves split KV 4-way; LDS merge at end.
// ---------------------------------------------------------------------------
__global__ __launch_bounds__(256, 4) void attn_kernel(
    const h16* __restrict__ Qh, const h16* __restrict__ Kh,
    const h16* __restrict__ VT, float* __restrict__ attd)
{
    __shared__ float st[4][64][10];
    const int t = threadIdx.x, w = t >> 6, lane = t & 63;
    const int h = blockIdx.x >> 8, qt = blockIdx.x & 255;
    const int l15 = lane & 15, g = lane >> 4;

    const h16* Kb = Kh + (size_t)h * 4096 * 32;
    const h16* Vb = VT + (size_t)h * 32 * 4096;
    half8 Qf = *(const half8*)(Qh + ((size_t)(h * 4096 + qt * 16 + l15) * 32 + g * 8));

    float m = -1e30f, l = 0.0f;
    f32x4 O0 = {0.f,0.f,0.f,0.f}, O1 = {0.f,0.f,0.f,0.f};
    const f32x4 zf = {0.f,0.f,0.f,0.f};
    const int sAlane = l15 + ((g & 1) << 5);
    const bool hi = g >= 2;

    const int kvbase = w * 1024;
    for (int kt = 0; kt < 32; ++kt) {
        int kv0 = kvbase + kt * 32;
        half8 K0 = *(const half8*)(Kb + ((size_t)(kv0 + l15) * 32 + g * 8));
        half8 K1 = *(const half8*)(Kb + ((size_t)(kv0 + 16 + l15) * 32 + g * 8));
        f32x4 S0 = __builtin_amdgcn_mfma_f32_16x16x32_f16(K0, Qf, zf, 0, 0, 0);
        f32x4 S1 = __builtin_amdgcn_mfma_f32_16x16x32_f16(K1, Qf, zf, 0, 0, 0);

        float tmax = fmaxf(fmaxf(fmaxf(S0.x, S0.y), fmaxf(S0.z, S0.w)),
                           fmaxf(fmaxf(S1.x, S1.y), fmaxf(S1.z, S1.w)));
        tmax = fmaxf(tmax, __shfl_xor(tmax, 16));
        tmax = fmaxf(tmax, __shfl_xor(tmax, 32));
        float mn = fmaxf(m, tmax);
        float c = __expf(m - mn);
        m = mn;
        float p0[4], p1[4];
        float ts = 0.f;
        #pragma unroll
        for (int i = 0; i < 4; ++i) { p0[i] = __expf(S0[i] - mn); ts += p0[i]; }
        #pragma unroll
        for (int i = 0; i < 4; ++i) { p1[i] = __expf(S1[i] - mn); ts += p1[i]; }
        ts += __shfl_xor(ts, 16);
        ts += __shfl_xor(ts, 32);
        l = l * c + ts;
        #pragma unroll
        for (int i = 0; i < 4; ++i) { O0[i] *= c; O1[i] *= c; }

        unsigned A0 = pk2h(p0[0], p0[1]), A1 = pk2h(p0[2], p0[3]);
        unsigned A2 = pk2h(p1[0], p1[1]), A3 = pk2h(p1[2], p1[3]);
        unsigned t0 = (unsigned)__shfl((int)A0, sAlane);
        unsigned t1 = (unsigned)__shfl((int)A1, sAlane);
        unsigned t2 = (unsigned)__shfl((int)A2, sAlane);
        unsigned t3 = (unsigned)__shfl((int)A3, sAlane);
        unsigned u0 = (unsigned)__shfl((int)A0, sAlane + 16);
        unsigned u1 = (unsigned)__shfl((int)A1, sAlane + 16);
        unsigned u2 = (unsigned)__shfl((int)A2, sAlane + 16);
        unsigned u3 = (unsigned)__shfl((int)A3, sAlane + 16);
        union { unsigned u[4]; half8 v; } P;
        P.u[0] = hi ? t2 : t0;
        P.u[1] = hi ? t3 : t1;
        P.u[2] = hi ? u2 : u0;
        P.u[3] = hi ? u3 : u1;

        half8 V0 = *(const half8*)(Vb + ((size_t)l15 * 4096 + kv0 + g * 8));
        half8 V1 = *(const half8*)(Vb + ((size_t)(16 + l15) * 4096 + kv0 + g * 8));
        O0 = __builtin_amdgcn_mfma_f32_16x16x32_f16(V0, P.v, O0, 0, 0, 0);
        O1 = __builtin_amdgcn_mfma_f32_16x16x32_f16(V1, P.v, O1, 0, 0, 0);
    }

    #pragma unroll
    for (int i = 0; i < 4; ++i) { st[w][lane][i] = O0[i]; st[w][lane][4 + i] = O1[i]; }
    st[w][lane][8] = m;
    st[w][lane][9] = l;
    __syncthreads();

    if (w == 0) {
        float M = -1e30f;
        #pragma unroll
        for (int j = 0; j < 4; ++j) M = fmaxf(M, st[j][lane][8]);
        float L = 0.f, o0[4] = {}, o1[4] = {};
        #pragma unroll
        for (int j = 0; j < 4; ++j) {
            float f = __expf(st[j][lane][8] - M);
            L += st[j][lane][9] * f;
            #pragma unroll
            for (int i = 0; i < 4; ++i) {
                o0[i] = fmaf(st[j][lane][i], f, o0[i]);
                o1[i] = fmaf(st[j][lane][4 + i], f, o1[i]);
            }
        }
        float invL = 1.0f / L;
        int nq = qt * 16 + l15;
        #pragma unroll
        for (int i = 0; i < 4; ++i) {
            attd[nq * 128 + h * 32 + g * 4 + i]      = o0[i] * invL;
            attd[nq * 128 + h * 32 + 16 + g * 4 + i] = o1[i] * invL;
        }
    }
}

// ---------------------------------------------------------------------------
extern "C" void kernel_launch(void* const* d_in, const int* in_sizes, int n_in,
                              void* d_out, int out_size, void* d_ws, size_t ws_size,
                              hipStream_t stream) {
    const int*   an    = (const int*)d_in[0];
    const int*   eidx  = (const int*)d_in[2];
    const float* evec  = (const float*)d_in[3];
    const float* elen  = (const float*)d_in[4];
    const float* emb   = (const float*)d_in[5];
    const float* Wr1   = (const float*)d_in[6];
    const float* br1   = (const float*)d_in[7];
    const float* Wr2   = (const float*)d_in[8];
    const float* br2   = (const float*)d_in[9];
    const float* Wtp   = (const float*)d_in[10];
    const float* btp   = (const float*)d_in[11];
    const float* Wm1   = (const float*)d_in[12];
    const float* bm1   = (const float*)d_in[13];
    const float* Wm2   = (const float*)d_in[14];
    const float* bm2   = (const float*)d_in[15];
    const float* Wqkv  = (const float*)d_in[16];
    const float* bqkv  = (const float*)d_in[17];
    const float* Wao   = (const float*)d_in[18];
    const float* bao   = (const float*)d_in[19];
    const float* Wg    = (const float*)d_in[20];
    const float* bg    = (const float*)d_in[21];
    const float* Wo    = (const float*)d_in[22];
    const float* bo    = (const float*)d_in[23];

    // workspace layout (floats), extent 4,456,448 f = 17.83 MB (R6-R14 proven):
    float* ws    = (float*)d_ws;
    float* agg   = ws;                       // [0, 262144)
    float* comb  = agg  + N_ATOMS * 64;      // [262144, 786432) region
    float* h1    = comb + N_ATOMS * 128;     // [786432, 1310720)
    float* upd   = h1   + N_ATOMS * 128;     // [1310720, 1835008)
    float* attd  = ws + 3407872;             // [3407872, 3932160)
    float* aob   = ws + 3932160;             // [3932160, 4456448)
    // time-disjoint aliases (liveness-audited):
    float* Wsl   = aob;                      // [3932160, 4005888); agg phase; aob written later
    int*   deg     = (int*)(aob + 73728);    // [4005888, 4009984)
    int*   base    = deg + 4096;
    int*   cur     = base + 4096;
    int*   sortedE = cur + 4096;             // ends 4149248 < 4456448; dead before aob write
    float* outp  = comb;                     // comb region free after attn
    h16* Qhb = (h16*)comb;                   // [262144, 524288) f32-equiv
    h16* Khb = Qhb + 4 * 4096 * 32;          // [524288, 786432)
    h16* VTb = (h16*)h1;                     // h1 dead after gemm m2

    hipMemsetAsync(deg, 0, 4096 * sizeof(int), stream);

    count_kernel<<<512, 256, 0, stream>>>(eidx, deg);
    scan_kernel<<<1, 1024, 0, stream>>>(deg, base, cur);
    scatter_kernel<<<512, 256, 0, stream>>>(eidx, cur, sortedE);

    wprep_kernel<<<288, 256, 0, stream>>>(Wtp, Wsl);

    agg_kernel<<<1024, 256, 0, stream>>>(
        evec, elen, sortedE, base, deg, Wr1, br1, Wr2, br2, Wsl, btp, agg);

    gemm_m1<<<dim3(64, 2), 256, 0, stream>>>(an, emb, agg, Wm1, bm1, h1);
    gemm128<0><<<dim3(64, 2), 256, 0, stream>>>(h1, Wm2, bm2, upd, 128, nullptr, nullptr);
    gemm_qkv<<<dim3(64, 6), 256, 0, stream>>>(upd, Wqkv, bqkv, Qhb, Khb, VTb);

    attn_kernel<<<1024, 256, 0, stream>>>(Qhb, Khb, VTb, attd);

    gemm128<0><<<dim3(64, 2), 256, 0, stream>>>(attd, Wao, bao, aob, 128, nullptr, nullptr);
    gemm128<2><<<dim3(64, 2), 256, 0, stream>>>(upd, Wg, bg, outp, 128, aob, upd);
    gemm128<0><<<dim3(64, 2), 256, 0, stream>>>(outp, Wo, bo, (float*)d_out, 128, nullptr, nullptr);
}